// Round 8
// baseline (127.455 us; speedup 1.0000x reference)
//
#include <hip/hip_runtime.h>

#define NROWS 131072
#define D 64
#define K 1024

typedef __attribute__((ext_vector_type(8))) short short8;
typedef __attribute__((ext_vector_type(4))) float f32x4;
typedef unsigned int u32;

// ws layout (bytes):
//   [0, 131072)        ehT  ushort[1024][64]  bf16 codebook, [code][d]
//   [131072, 135168)   e2g  float[1024]       = -0.5*||e_k||^2
//   [135168, 139264)   hist int[1024]
//   [139264, 143360)   wavesum float[256]  (one per score block)

__device__ __forceinline__ unsigned short f2bf_rne(float f) {
    u32 u = __float_as_uint(f);
    u += 0x7fff + ((u >> 16) & 1);   // round-to-nearest-even
    return (unsigned short)(u >> 16);
}

__device__ __forceinline__ float b2f(short s) {
    return __uint_as_float(((u32)(unsigned short)s) << 16);
}

// 16 blocks x 256 threads: block handles 64 codes, thread = (code, d-quarter).
__global__ __launch_bounds__(256) void prep_kernel(const float* __restrict__ E,
                                                   unsigned short* __restrict__ ehT,
                                                   float* __restrict__ e2g,
                                                   int* __restrict__ hist) {
    __shared__ float ps[4][64];
    const int lane = threadIdx.x & 63;          // code offset within block
    const int w = threadIdx.x >> 6;             // d-quarter 0..3
    const int k = blockIdx.x * 64 + lane;
    float s = 0.f;
#pragma unroll
    for (int half = 0; half < 2; ++half) {
        short8 h8;
#pragma unroll
        for (int j = 0; j < 8; ++j) {
            float v = E[(w * 16 + half * 8 + j) * K + k];   // coalesced across lanes
            s = fmaf(v, v, s);
            h8[j] = (short)f2bf_rne(v);
        }
        *(short8*)(ehT + (size_t)k * D + w * 16 + half * 8) = h8;
    }
    ps[w][lane] = s;
    __syncthreads();
    if (w == 0) e2g[k] = -0.5f * (ps[0][lane] + ps[1][lane] + ps[2][lane] + ps[3][lane]);
    if (threadIdx.x < 64) hist[blockIdx.x * 64 + threadIdx.x] = 0;
}

// R14: superchunk restructure — attack barrier lockstep, the last un-modeled
// invariant. Evidence: 6 structural variants all land 49-57us while every
// pipe is <=30% busy (overlapped floor ~15us); the common factor is 9
// barriers/block with vmcnt(0) drains synchronizing all 16 waves' stalls.
// Changes vs R7 (49.3us):
//  (1) stage ALL 4 chunks in 64KB LDS (was 2x16KB dbuf); process superchunks
//      of 16 t-iters. Barriers 9 -> 5; between B3(sc0) and B2(sc1) waves
//      free-run through epilogue(sc0)+compute(sc1) with NO barrier.
//  (2) hist atomicAdd moved OUT of the barrier window (merge is pure LDS;
//      atomics fire after B3, latency hidden under epilogue/compute).
//  (3) revert R7's batched bt8 reduce (measured zero) -> inline per-t reduce,
//      keeps regs ~96 < 128 (launch_bounds(1024) cap; R2-R4 lesson: spill
//      canary = WRITE_SIZE > 36.2MB).
// Numerics: identical scores, merge, per-thread ls chain order; hist order
// commutative -> absmax must be EXACTLY 0.4326172 (bitwise canary).
__global__ __launch_bounds__(1024) void score_kernel(const float* __restrict__ X,
                                                     const unsigned short* __restrict__ ehT,
                                                     const float* __restrict__ e2g,
                                                     int* __restrict__ hist,
                                                     float* __restrict__ wavesum,
                                                     float* __restrict__ q) {
    __shared__ unsigned short xbuf[4][8192];   // 64 KB: 4 chunks x 128 rows x 64 d, frag order
    __shared__ float mrg[256 * 17];            // per-row packed best per wave (stride 17)
    __shared__ int idxl[2][256];               // winning code per row, per superchunk
    __shared__ float redL[16];

    const int tid = threadIdx.x;
    const int wave = tid >> 6;
    const int lane = tid & 63;
    const int quad = lane >> 4;
    const int lc = lane & 15;
    const size_t row0 = (size_t)blockIdx.x * 512;

    // ---- stage mapping: thread n -> LDS 16B unit n of each chunk =
    // (t=n>>7, o=(n>>4)&7, ls=n&15) holding bf16 X[t*16+ls][o*8..+8].
    const int st = tid >> 7, so = (tid >> 4) & 7, sl = tid & 15;
    const int rowl = st * 16 + sl;             // this thread's staged row (0..127)
    const float* sbase = X + (row0 + (size_t)rowl) * D + so * 8;

    // ---- prologue: stage chunks 0,1 (loads first, then pack+write) ----
    {
        float4 L0a = *(const float4*)(sbase);
        float4 L0b = *(const float4*)(sbase + 4);
        float4 L1a = *(const float4*)(sbase + 8192);
        float4 L1b = *(const float4*)(sbase + 8192 + 4);
        union { u32 u[4]; short8 v; } pk;
        pk.u[0] = __builtin_amdgcn_perm(__float_as_uint(L0a.y), __float_as_uint(L0a.x), 0x07060302);
        pk.u[1] = __builtin_amdgcn_perm(__float_as_uint(L0a.w), __float_as_uint(L0a.z), 0x07060302);
        pk.u[2] = __builtin_amdgcn_perm(__float_as_uint(L0b.y), __float_as_uint(L0b.x), 0x07060302);
        pk.u[3] = __builtin_amdgcn_perm(__float_as_uint(L0b.w), __float_as_uint(L0b.z), 0x07060302);
        *(short8*)((char*)&xbuf[0][0] + tid * 16) = pk.v;
        pk.u[0] = __builtin_amdgcn_perm(__float_as_uint(L1a.y), __float_as_uint(L1a.x), 0x07060302);
        pk.u[1] = __builtin_amdgcn_perm(__float_as_uint(L1a.w), __float_as_uint(L1a.z), 0x07060302);
        pk.u[2] = __builtin_amdgcn_perm(__float_as_uint(L1b.y), __float_as_uint(L1b.x), 0x07060302);
        pk.u[3] = __builtin_amdgcn_perm(__float_as_uint(L1b.w), __float_as_uint(L1b.z), 0x07060302);
        *(short8*)((char*)&xbuf[1][0] + tid * 16) = pk.v;
    }

    // ---- persistent codebook fragments: wave owns codes [wave*64, wave*64+64) ----
    const int cbase = wave * 64;
    short8 ae[4][2];      // [code-tile][kslice]: code=tile*16+lc, d=ks*32+quad*8..+8
    f32x4 e2f[4];         // -0.5||e||^2 for codes tile*16+quad*4..+4 (MFMA C operand)
#pragma unroll
    for (int ct = 0; ct < 4; ++ct) {
        const unsigned short* ap = ehT + ((size_t)(cbase + ct * 16 + lc) << 6) + quad * 8;
        ae[ct][0] = *(const short8*)(ap);
        ae[ct][1] = *(const short8*)(ap + 32);
        e2f[ct] = *(const f32x4*)(e2g + cbase + ct * 16 + quad * 4);
    }
    const u32 cb0 = (u32)(cbase + quad * 4);

    __syncthreads();   // B1: chunks 0,1 staged

    float ls = 0.f;
    float4 P2a, P2b, P3a, P3b;   // pending loads for chunks 2,3 (sc0 only)
    for (int sc = 0; sc < 2; ++sc) {
        if (sc == 0) {
            // issue-early: chunks 2,3 land during sc0 compute (~16 t-iters)
            P2a = *(const float4*)(sbase + 2 * 8192);
            P2b = *(const float4*)(sbase + 2 * 8192 + 4);
            P3a = *(const float4*)(sbase + 3 * 8192);
            P3b = *(const float4*)(sbase + 3 * 8192 + 4);
        }

        // ---- compute superchunk sc: 16 row-tiles, free-running ----
        const char* bb = (const char*)&xbuf[sc * 2][0];   // 32 KB contiguous
#pragma unroll 2
        for (int t = 0; t < 16; ++t) {
            const char* bp = bb + t * 2048 + quad * 256 + lc * 16;
            short8 b0 = *(const short8*)(bp);           // ks0
            short8 b1 = *(const short8*)(bp + 1024);    // ks1
            float bt = -3.4e38f;
#pragma unroll
            for (int ct = 0; ct < 4; ++ct) {
                f32x4 acc = __builtin_amdgcn_mfma_f32_16x16x32_bf16(ae[ct][0], b0, e2f[ct], 0, 0, 0);
                acc = __builtin_amdgcn_mfma_f32_16x16x32_bf16(ae[ct][1], b1, acc, 0, 0, 0);
                // acc[r] = score(code = cb0 + ct*16 + r, xrow = t*16+lc)
                float p0 = __uint_as_float((__float_as_uint(acc[0]) & 0xFFFFFC00u) | (cb0 + ct * 16 + 0));
                float p1 = __uint_as_float((__float_as_uint(acc[1]) & 0xFFFFFC00u) | (cb0 + ct * 16 + 1));
                float p2 = __uint_as_float((__float_as_uint(acc[2]) & 0xFFFFFC00u) | (cb0 + ct * 16 + 2));
                float p3 = __uint_as_float((__float_as_uint(acc[3]) & 0xFFFFFC00u) | (cb0 + ct * 16 + 3));
                bt = fmaxf(bt, fmaxf(p0, p1));   // v_max3
                bt = fmaxf(bt, fmaxf(p2, p3));   // v_max3
            }
            bt = fmaxf(bt, __shfl_xor(bt, 16, 64));
            bt = fmaxf(bt, __shfl_xor(bt, 32, 64));
            if (lane < 16) mrg[(t * 16 + lane) * 17 + wave] = bt;
        }
        __syncthreads();   // B2: mrg visible

        // ---- merge (pure LDS, 256 thr) ∥ stage-write chunks 2,3 (sc0, all) ----
        if (tid < 256) {
            float m = mrg[tid * 17];
#pragma unroll
            for (int w = 1; w < 16; ++w) m = fmaxf(m, mrg[tid * 17 + w]);
            idxl[sc][tid] = (int)(__float_as_uint(m) & 1023u);
        }
        if (sc == 0) {
            union { u32 u[4]; short8 v; } pk;
            pk.u[0] = __builtin_amdgcn_perm(__float_as_uint(P2a.y), __float_as_uint(P2a.x), 0x07060302);
            pk.u[1] = __builtin_amdgcn_perm(__float_as_uint(P2a.w), __float_as_uint(P2a.z), 0x07060302);
            pk.u[2] = __builtin_amdgcn_perm(__float_as_uint(P2b.y), __float_as_uint(P2b.x), 0x07060302);
            pk.u[3] = __builtin_amdgcn_perm(__float_as_uint(P2b.w), __float_as_uint(P2b.z), 0x07060302);
            *(short8*)((char*)&xbuf[2][0] + tid * 16) = pk.v;
            pk.u[0] = __builtin_amdgcn_perm(__float_as_uint(P3a.y), __float_as_uint(P3a.x), 0x07060302);
            pk.u[1] = __builtin_amdgcn_perm(__float_as_uint(P3a.w), __float_as_uint(P3a.z), 0x07060302);
            pk.u[2] = __builtin_amdgcn_perm(__float_as_uint(P3b.y), __float_as_uint(P3b.x), 0x07060302);
            pk.u[3] = __builtin_amdgcn_perm(__float_as_uint(P3b.w), __float_as_uint(P3b.z), 0x07060302);
            *(short8*)((char*)&xbuf[3][0] + tid * 16) = pk.v;
        }
        __syncthreads();   // B3: idxl[sc] (+ staged chunks 2,3) visible

        // ---- hist atomics: fire-and-forget, latency hidden under epilogue ----
        if (tid < 256) atomicAdd(&hist[idxl[sc][tid]], 1);

        // ---- fused epilogue sc: own staged slices; q = e_bf16; no X read.
        // Flows straight into sc1 compute with NO barrier (free-run stretch).
#pragma unroll
        for (int h = 0; h < 2; ++h) {
            const int cc = sc * 2 + h;
            int kk = idxl[sc][h * 128 + rowl];        // broadcast among 8 so-threads
            short8 ev = *(const short8*)(ehT + ((size_t)kk << 6) + so * 8);
            short8 xv = *(const short8*)(&xbuf[cc][tid * 8]);
            float4 qa, qb;
            float e0, dd;
            e0 = b2f(ev[0]); dd = e0 - b2f(xv[0]); ls = fmaf(dd, dd, ls); qa.x = e0;
            e0 = b2f(ev[1]); dd = e0 - b2f(xv[1]); ls = fmaf(dd, dd, ls); qa.y = e0;
            e0 = b2f(ev[2]); dd = e0 - b2f(xv[2]); ls = fmaf(dd, dd, ls); qa.z = e0;
            e0 = b2f(ev[3]); dd = e0 - b2f(xv[3]); ls = fmaf(dd, dd, ls); qa.w = e0;
            e0 = b2f(ev[4]); dd = e0 - b2f(xv[4]); ls = fmaf(dd, dd, ls); qb.x = e0;
            e0 = b2f(ev[5]); dd = e0 - b2f(xv[5]); ls = fmaf(dd, dd, ls); qb.y = e0;
            e0 = b2f(ev[6]); dd = e0 - b2f(xv[6]); ls = fmaf(dd, dd, ls); qb.z = e0;
            e0 = b2f(ev[7]); dd = e0 - b2f(xv[7]); ls = fmaf(dd, dd, ls); qb.w = e0;
            float* qp = q + (row0 + (size_t)(cc * 128 + rowl)) * D + so * 8;
            *(float4*)(qp) = qa;
            *(float4*)(qp + 4) = qb;
        }
    }

    // ---- block loss reduction ----
    for (int off = 32; off > 0; off >>= 1) ls += __shfl_down(ls, off, 64);
    if (lane == 0) redL[wave] = ls;
    __syncthreads();
    if (tid == 0) {
        float L = 0.f;
#pragma unroll
        for (int i = 0; i < 16; ++i) L += redL[i];
        wavesum[blockIdx.x] = L;
    }
}

__global__ __launch_bounds__(1024) void finalize_kernel(const int* __restrict__ hist,
                                                        const float* __restrict__ wavesum,
                                                        float* __restrict__ out) {
    __shared__ float redH[16], redL[16];
    int tid = threadIdx.x;
    float p = (float)hist[tid] * (1.0f / (float)NROWS);
    float term = p * logf(p + 1e-10f);
    float ls = (tid < 256) ? wavesum[tid] : 0.f;
    for (int off = 32; off > 0; off >>= 1) {
        term += __shfl_down(term, off, 64);
        ls += __shfl_down(ls, off, 64);
    }
    int lane = tid & 63, wid = tid >> 6;
    if (lane == 0) { redH[wid] = term; redL[wid] = ls; }
    __syncthreads();
    if (tid == 0) {
        float H = 0.f, L = 0.f;
#pragma unroll
        for (int i = 0; i < 16; ++i) { H += redH[i]; L += redL[i]; }
        out[(size_t)NROWS * D + 0] = 2.0f * (L / (float)(NROWS * D));
        out[(size_t)NROWS * D + 1] = expf(-H);
    }
}

extern "C" void kernel_launch(void* const* d_in, const int* in_sizes, int n_in,
                              void* d_out, int out_size, void* d_ws, size_t ws_size,
                              hipStream_t stream) {
    const float* X = (const float*)d_in[0];   // [64,2048,64] fp32
    const float* E = (const float*)d_in[1];   // [64,1024]   fp32
    float* out = (float*)d_out;

    char* w = (char*)d_ws;
    unsigned short* ehT = (unsigned short*)(w + 0);
    float* e2g          = (float*)(w + 131072);
    int* hist           = (int*)(w + 135168);
    float* wavesum      = (float*)(w + 139264);

    prep_kernel<<<16, 256, 0, stream>>>(E, ehT, e2g, hist);
    score_kernel<<<NROWS / 512, 1024, 0, stream>>>(X, ehT, e2g, hist, wavesum, out);
    finalize_kernel<<<1, 1024, 0, stream>>>(hist, wavesum, out);
}

// Round 11
// 122.555 us; speedup vs baseline: 1.0400x; 1.0400x over previous
//
#include <hip/hip_runtime.h>

#define NROWS 131072
#define D 64
#define K 1024

typedef __attribute__((ext_vector_type(8))) short short8;
typedef __attribute__((ext_vector_type(4))) float f32x4;
typedef unsigned int u32;

// ws layout (bytes):
//   [0, 131072)        ehT  ushort[1024][64]  bf16 codebook, [code][d]
//   [131072, 135168)   e2g  float[1024]       = -0.5*||e_k||^2
//   [135168, 139264)   hist int[1024]
//   [139264, 143360)   wavesum float[256]  (one per score block)

__device__ __forceinline__ unsigned short f2bf_rne(float f) {
    u32 u = __float_as_uint(f);
    u += 0x7fff + ((u >> 16) & 1);   // round-to-nearest-even
    return (unsigned short)(u >> 16);
}

__device__ __forceinline__ float b2f(short s) {
    return __uint_as_float(((u32)(unsigned short)s) << 16);
}

// 16 blocks x 256 threads: block handles 64 codes, thread = (code, d-quarter).
__global__ __launch_bounds__(256) void prep_kernel(const float* __restrict__ E,
                                                   unsigned short* __restrict__ ehT,
                                                   float* __restrict__ e2g,
                                                   int* __restrict__ hist) {
    __shared__ float ps[4][64];
    const int lane = threadIdx.x & 63;          // code offset within block
    const int w = threadIdx.x >> 6;             // d-quarter 0..3
    const int k = blockIdx.x * 64 + lane;
    float s = 0.f;
#pragma unroll
    for (int half = 0; half < 2; ++half) {
        short8 h8;
#pragma unroll
        for (int j = 0; j < 8; ++j) {
            float v = E[(w * 16 + half * 8 + j) * K + k];   // coalesced across lanes
            s = fmaf(v, v, s);
            h8[j] = (short)f2bf_rne(v);
        }
        *(short8*)(ehT + (size_t)k * D + w * 16 + half * 8) = h8;
    }
    ps[w][lane] = s;
    __syncthreads();
    if (w == 0) e2g[k] = -0.5f * (ps[0][lane] + ps[1][lane] + ps[2][lane] + ps[3][lane]);
    if (threadIdx.x < 64) hist[blockIdx.x * 64 + threadIdx.x] = 0;
}

// R17 = R16 with the compile fix: __builtin_nontemporal_store requires a
// clang ext_vector pointee (f32x4), not HIP's float4 struct.
// Theory unchanged: R7 (best verified: score 49.3us, total 122.1us) + ONE
// change — nontemporal q stores. q is 33.5MB write-once/never-re-read traffic
// that (a) leaves L2 dirty at the kernel boundary and (b) evicts the X/ehT
// lines that give the 50% L3 hit rate on X (FETCH 17MB vs 33.5MB of X reads).
// Numerics: identical operands + MFMA chain + packed score|code argmax ->
// absmax must be exactly 0.4326172.
__global__ __launch_bounds__(1024) void score_kernel(const float* __restrict__ X,
                                                     const unsigned short* __restrict__ ehT,
                                                     const float* __restrict__ e2g,
                                                     int* __restrict__ hist,
                                                     float* __restrict__ wavesum,
                                                     float* __restrict__ q) {
    __shared__ unsigned short xbuf[2][8192];   // 2 x 16 KB: 128 rows x 64 d, frag order
    __shared__ float mrg[2][128 * 17];         // per-row packed best per wave (stride 17)
    __shared__ int idxl[2][128];               // winning code per row, double-buffered
    __shared__ float redL[16];

    const int tid = threadIdx.x;
    const int wave = tid >> 6;
    const int lane = tid & 63;
    const int quad = lane >> 4;
    const int lc = lane & 15;
    const size_t row0 = (size_t)blockIdx.x * 512;

    // ---- stage mapping: thread n -> LDS 16B unit n = (t=n>>7, o=(n>>4)&7,
    // ls=n&15) holding bf16 X[t*16+ls][o*8..+8]; global read fully coalesced.
    const int st = tid >> 7, so = (tid >> 4) & 7, sl = tid & 15;
    const int rowl = st * 16 + sl;             // this thread's staged row (0..127)
    const float* sbase = X + (row0 + (size_t)rowl) * D + so * 8;

    // ---- prologue: stage chunk 0 ----
    {
        float4 La = *(const float4*)(sbase);
        float4 Lb = *(const float4*)(sbase + 4);
        union { u32 u[4]; short8 v; } pk;
        pk.u[0] = __builtin_amdgcn_perm(__float_as_uint(La.y), __float_as_uint(La.x), 0x07060302);
        pk.u[1] = __builtin_amdgcn_perm(__float_as_uint(La.w), __float_as_uint(La.z), 0x07060302);
        pk.u[2] = __builtin_amdgcn_perm(__float_as_uint(Lb.y), __float_as_uint(Lb.x), 0x07060302);
        pk.u[3] = __builtin_amdgcn_perm(__float_as_uint(Lb.w), __float_as_uint(Lb.z), 0x07060302);
        *(short8*)((char*)&xbuf[0][0] + tid * 16) = pk.v;
    }

    // ---- persistent codebook fragments: wave owns codes [wave*64, wave*64+64) ----
    const int cbase = wave * 64;
    short8 ae[4][2];      // [code-tile][kslice]: code=tile*16+lc, d=ks*32+quad*8..+8
    f32x4 e2f[4];         // -0.5||e||^2 for codes tile*16+quad*4..+4 (MFMA C operand)
#pragma unroll
    for (int ct = 0; ct < 4; ++ct) {
        const unsigned short* ap = ehT + ((size_t)(cbase + ct * 16 + lc) << 6) + quad * 8;
        ae[ct][0] = *(const short8*)(ap);
        ae[ct][1] = *(const short8*)(ap + 32);
        e2f[ct] = *(const f32x4*)(e2g + cbase + ct * 16 + quad * 4);
    }
    const u32 cb0 = (u32)(cbase + quad * 4);

    __syncthreads();   // B1: chunk 0 staged

    float ls = 0.f;
    for (int c = 0; c < 4; ++c) {
        const int cur = c & 1;
        // issue-early global loads for chunk c+1 (land during compute; the
        // vmcnt wait sits at the stage-write after B2, long past latency)
        float4 La, Lb;
        if (c < 3) {
            La = *(const float4*)(sbase + (c + 1) * 8192);
            Lb = *(const float4*)(sbase + (c + 1) * 8192 + 4);
        }

        // ---- compute chunk c: pure ds_read + MFMA + max3 into bt8 ----
        float bt8[8];
        const char* bb = (const char*)&xbuf[cur][0];
#pragma unroll 2
        for (int t = 0; t < 8; ++t) {
            const char* bp = bb + t * 2048 + quad * 256 + lc * 16;
            short8 b0 = *(const short8*)(bp);           // ks0
            short8 b1 = *(const short8*)(bp + 1024);    // ks1
            float bt = -3.4e38f;
#pragma unroll
            for (int ct = 0; ct < 4; ++ct) {
                f32x4 acc = __builtin_amdgcn_mfma_f32_16x16x32_bf16(ae[ct][0], b0, e2f[ct], 0, 0, 0);
                acc = __builtin_amdgcn_mfma_f32_16x16x32_bf16(ae[ct][1], b1, acc, 0, 0, 0);
                // acc[r] = score(code = cb0 + ct*16 + r, xrow = t*16+lc)
                float p0 = __uint_as_float((__float_as_uint(acc[0]) & 0xFFFFFC00u) | (cb0 + ct * 16 + 0));
                float p1 = __uint_as_float((__float_as_uint(acc[1]) & 0xFFFFFC00u) | (cb0 + ct * 16 + 1));
                float p2 = __uint_as_float((__float_as_uint(acc[2]) & 0xFFFFFC00u) | (cb0 + ct * 16 + 2));
                float p3 = __uint_as_float((__float_as_uint(acc[3]) & 0xFFFFFC00u) | (cb0 + ct * 16 + 3));
                bt = fmaxf(bt, fmaxf(p0, p1));   // v_max3
                bt = fmaxf(bt, fmaxf(p2, p3));   // v_max3
            }
            bt8[t] = bt;
        }
        // ---- batched cross-lane reduce: 8 independent shfl chains ----
#pragma unroll
        for (int t = 0; t < 8; ++t) {
            float bt = bt8[t];
            bt = fmaxf(bt, __shfl_xor(bt, 16, 64));
            bt = fmaxf(bt, __shfl_xor(bt, 32, 64));
            if (lane < 16) mrg[cur][(t * 16 + lane) * 17 + wave] = bt;
        }
        __syncthreads();   // B2: mrg[cur] visible

        // ---- merge (128 thr) ∥ stage-write c+1 (all) ----
        if (tid < 128) {
            float m = mrg[cur][tid * 17];
#pragma unroll
            for (int w = 1; w < 16; ++w) m = fmaxf(m, mrg[cur][tid * 17 + w]);
            int kk = (int)(__float_as_uint(m) & 1023u);
            idxl[cur][tid] = kk;
            atomicAdd(&hist[kk], 1);
        }
        if (c < 3) {
            union { u32 u[4]; short8 v; } pk;
            pk.u[0] = __builtin_amdgcn_perm(__float_as_uint(La.y), __float_as_uint(La.x), 0x07060302);
            pk.u[1] = __builtin_amdgcn_perm(__float_as_uint(La.w), __float_as_uint(La.z), 0x07060302);
            pk.u[2] = __builtin_amdgcn_perm(__float_as_uint(Lb.y), __float_as_uint(Lb.x), 0x07060302);
            pk.u[3] = __builtin_amdgcn_perm(__float_as_uint(Lb.w), __float_as_uint(Lb.z), 0x07060302);
            *(short8*)((char*)&xbuf[cur ^ 1][0] + tid * 16) = pk.v;
        }
        __syncthreads();   // B3: idxl[cur] + staged chunk visible

        // ---- fused epilogue chunk c: own staged slice; q = e_bf16; no X read.
        // Nontemporal ext-vector stores: q is write-once, keep it out of L2.
        {
            int kk = idxl[cur][rowl];                 // broadcast among 8 so-threads
            short8 ev = *(const short8*)(ehT + ((size_t)kk << 6) + so * 8);
            short8 xv = *(const short8*)(&xbuf[cur][tid * 8]);
            f32x4 qa, qb;
            float e0, dd;
            e0 = b2f(ev[0]); dd = e0 - b2f(xv[0]); ls = fmaf(dd, dd, ls); qa.x = e0;
            e0 = b2f(ev[1]); dd = e0 - b2f(xv[1]); ls = fmaf(dd, dd, ls); qa.y = e0;
            e0 = b2f(ev[2]); dd = e0 - b2f(xv[2]); ls = fmaf(dd, dd, ls); qa.z = e0;
            e0 = b2f(ev[3]); dd = e0 - b2f(xv[3]); ls = fmaf(dd, dd, ls); qa.w = e0;
            e0 = b2f(ev[4]); dd = e0 - b2f(xv[4]); ls = fmaf(dd, dd, ls); qb.x = e0;
            e0 = b2f(ev[5]); dd = e0 - b2f(xv[5]); ls = fmaf(dd, dd, ls); qb.y = e0;
            e0 = b2f(ev[6]); dd = e0 - b2f(xv[6]); ls = fmaf(dd, dd, ls); qb.z = e0;
            e0 = b2f(ev[7]); dd = e0 - b2f(xv[7]); ls = fmaf(dd, dd, ls); qb.w = e0;
            float* qp = q + (row0 + (size_t)(c * 128 + rowl)) * D + so * 8;
            __builtin_nontemporal_store(qa, (f32x4*)(qp));
            __builtin_nontemporal_store(qb, (f32x4*)(qp + 4));
        }
    }

    // ---- block loss reduction ----
    for (int off = 32; off > 0; off >>= 1) ls += __shfl_down(ls, off, 64);
    if (lane == 0) redL[wave] = ls;
    __syncthreads();
    if (tid == 0) {
        float L = 0.f;
#pragma unroll
        for (int i = 0; i < 16; ++i) L += redL[i];
        wavesum[blockIdx.x] = L;
    }
}

__global__ __launch_bounds__(1024) void finalize_kernel(const int* __restrict__ hist,
                                                        const float* __restrict__ wavesum,
                                                        float* __restrict__ out) {
    __shared__ float redH[16], redL[16];
    int tid = threadIdx.x;
    float p = (float)hist[tid] * (1.0f / (float)NROWS);
    float term = p * logf(p + 1e-10f);
    float ls = (tid < 256) ? wavesum[tid] : 0.f;
    for (int off = 32; off > 0; off >>= 1) {
        term += __shfl_down(term, off, 64);
        ls += __shfl_down(ls, off, 64);
    }
    int lane = tid & 63, wid = tid >> 6;
    if (lane == 0) { redH[wid] = term; redL[wid] = ls; }
    __syncthreads();
    if (tid == 0) {
        float H = 0.f, L = 0.f;
#pragma unroll
        for (int i = 0; i < 16; ++i) { H += redH[i]; L += redL[i]; }
        out[(size_t)NROWS * D + 0] = 2.0f * (L / (float)(NROWS * D));
        out[(size_t)NROWS * D + 1] = expf(-H);
    }
}

extern "C" void kernel_launch(void* const* d_in, const int* in_sizes, int n_in,
                              void* d_out, int out_size, void* d_ws, size_t ws_size,
                              hipStream_t stream) {
    const float* X = (const float*)d_in[0];   // [64,2048,64] fp32
    const float* E = (const float*)d_in[1];   // [64,1024]   fp32
    float* out = (float*)d_out;

    char* w = (char*)d_ws;
    unsigned short* ehT = (unsigned short*)(w + 0);
    float* e2g          = (float*)(w + 131072);
    int* hist           = (int*)(w + 135168);
    float* wavesum      = (float*)(w + 139264);

    prep_kernel<<<16, 256, 0, stream>>>(E, ehT, e2g, hist);
    score_kernel<<<NROWS / 512, 1024, 0, stream>>>(X, ehT, e2g, hist, wavesum, out);
    finalize_kernel<<<1, 1024, 0, stream>>>(hist, wavesum, out);
}